// Round 11
// baseline (1620.980 us; speedup 1.0000x reference)
//
#include <hip/hip_runtime.h>
#include <hip/hip_bf16.h>

#define HID 50
#define FOURH 200
#define TSTEPS 2048
#define NBATCH 1024
#define NT 13              // 13 N-tiles x 16 = 208 >= 200

typedef _Float16 half8 __attribute__((ext_vector_type(8)));
typedef _Float16 half2t __attribute__((ext_vector_type(2)));
typedef float    f32x4 __attribute__((ext_vector_type(4)));

#define LOG2E 1.44269504f

__device__ __forceinline__ float frcp(float x)  { return __builtin_amdgcn_rcpf(x); }
__device__ __forceinline__ float fexp2(float x) { return __builtin_amdgcn_exp2f(x); }
__device__ __forceinline__ float fast_sigmoid(float x) {
    return frcp(1.0f + fexp2(-LOG2E * x));                       // NaN-free tails
}
__device__ __forceinline__ float fast_tanh(float x) {
    return 1.0f - 2.0f * frcp(fexp2((2.0f * LOG2E) * x) + 1.0f); // saturating
}
__device__ __forceinline__ float bperm_f(int byte_addr, float v) {
    return __int_as_float(__builtin_amdgcn_ds_bpermute(byte_addr, __float_as_int(v)));
}

// Single wave per batch, ZERO barriers. The wave computes the full
// Z[row0, 208] = h[50] @ Wh via 13 tiles x 2 chained 16x16x32_f16 MFMAs with
// all 26 B-frags resident in VGPRs (B rows k>=50 are ZERO, so A-garbage in
// those slots is harmless). A-frags are gathered from the per-lane h register
// with 16 ds_bpermute + 8 cvt_pkrtz (no h LDS round-trip). Z row 0 (q==0
// lanes, acc[0]) -> 13 ds_write_b32 -> 4 scalar reads per lane (same-wave
// in-order DS pipe, no barrier; 2-way bank aliasing = free). Act phase is
// per-lane fp32 (R6 numerics), x/bias folded there. 1024 waves = 1/SIMD.
__global__ __launch_bounds__(64, 1)
void lstm_wmfma_kernel(const float* __restrict__ x,
                       const float* __restrict__ Wx,
                       const float* __restrict__ Wh,
                       const float* __restrict__ bias,
                       const float* __restrict__ Wd,
                       const float* __restrict__ bd,
                       float* __restrict__ out) {
    const int b    = blockIdx.x;
    const int lane = threadIdx.x;
    const int ln16 = lane & 15;      // n within tile / A row m
    const int q    = lane >> 4;      // quad
    const int u    = (lane < HID) ? lane : (HID - 1);   // act unit (clamped)

    __shared__ __align__(16) float xs[TSTEPS + 4];
    __shared__ __align__(16) float zsh[224];            // 208 z cols (+pad)

    // Stage x (coalesced float4).
    const float4* xb4 = (const float4*)(x + (size_t)b * TSTEPS);
    float4* xs4 = (float4*)xs;
    #pragma unroll
    for (int i = lane; i < TSTEPS / 4; i += 64) xs4[i] = xb4[i];
    if (lane == 0) xs[TSTEPS] = 0.0f;

    // B-fragments: B[n=ln16 within tile][k=q*8+j]; rows k>=50 ZERO.
    half8 bf0[NT], bf1[NT];
    #pragma unroll
    for (int tile = 0; tile < NT; ++tile) {
        const int n = tile * 16 + ln16;
        half8 b0, b1;
        #pragma unroll
        for (int j = 0; j < 8; ++j) {
            const int k0 = q * 8 + j;        // 0..31, always < 50
            const int k1 = k0 + 32;          // 32..63
            b0[j] = (n < FOURH) ? (_Float16)Wh[k0 * FOURH + n] : (_Float16)0.0f;
            b1[j] = (n < FOURH && k1 < HID) ? (_Float16)Wh[k1 * FOURH + n]
                                            : (_Float16)0.0f;
        }
        bf0[tile] = b0; bf1[tile] = b1;
    }

    // Act constants for unit u (all 4 gates), fp32.
    const float wx_i = Wx[u],            b_i = bias[u];
    const float wx_f = Wx[HID + u],      b_f = bias[HID + u];
    const float wx_g = Wx[2 * HID + u],  b_g = bias[2 * HID + u];
    const float wx_o = Wx[3 * HID + u],  b_o = bias[3 * HID + u];
    const float wd_u = Wd[u];

    // bpermute byte addrs for A-gather: a0 k=0..31, a1 k=32..63 (clamped; the
    // clamped slots multiply zero B rows).
    int adr0[8], adr1[8];
    #pragma unroll
    for (int j = 0; j < 8; ++j) {
        const int k0 = q * 8 + j;
        const int k1 = 32 + k0;
        adr0[j] = 4 * k0;
        adr1[j] = 4 * ((k1 < HID) ? k1 : (HID - 1));
    }

    float c = 0.0f, h = 0.0f;
    __syncthreads();   // one-time: xs visible (single wave, cheap)

    float xt = xs[0];

    for (int t = 0; t < TSTEPS; ++t) {
        const float xt_next = xs[t + 1];

        // ---- A-gather: h register -> half8 frags via bpermute + pack ----
        uint2 p0a, p0b, p1a, p1b;
        {
            float g0 = bperm_f(adr0[0], h), g1 = bperm_f(adr0[1], h);
            float g2 = bperm_f(adr0[2], h), g3 = bperm_f(adr0[3], h);
            float g4 = bperm_f(adr0[4], h), g5 = bperm_f(adr0[5], h);
            float g6 = bperm_f(adr0[6], h), g7 = bperm_f(adr0[7], h);
            p0a.x = __builtin_bit_cast(unsigned int, __builtin_amdgcn_cvt_pkrtz(g0, g1));
            p0a.y = __builtin_bit_cast(unsigned int, __builtin_amdgcn_cvt_pkrtz(g2, g3));
            p0b.x = __builtin_bit_cast(unsigned int, __builtin_amdgcn_cvt_pkrtz(g4, g5));
            p0b.y = __builtin_bit_cast(unsigned int, __builtin_amdgcn_cvt_pkrtz(g6, g7));
            float e0 = bperm_f(adr1[0], h), e1 = bperm_f(adr1[1], h);
            float e2 = bperm_f(adr1[2], h), e3 = bperm_f(adr1[3], h);
            float e4 = bperm_f(adr1[4], h), e5 = bperm_f(adr1[5], h);
            float e6 = bperm_f(adr1[6], h), e7 = bperm_f(adr1[7], h);
            p1a.x = __builtin_bit_cast(unsigned int, __builtin_amdgcn_cvt_pkrtz(e0, e1));
            p1a.y = __builtin_bit_cast(unsigned int, __builtin_amdgcn_cvt_pkrtz(e2, e3));
            p1b.x = __builtin_bit_cast(unsigned int, __builtin_amdgcn_cvt_pkrtz(e4, e5));
            p1b.y = __builtin_bit_cast(unsigned int, __builtin_amdgcn_cvt_pkrtz(e6, e7));
        }
        const uint4 u0 = {p0a.x, p0a.y, p0b.x, p0b.y};
        const uint4 u1 = {p1a.x, p1a.y, p1b.x, p1b.y};
        const half8 a0 = __builtin_bit_cast(half8, u0);
        const half8 a1 = __builtin_bit_cast(half8, u1);

        // ---- 13 tiles x 2 MFMA; q==0 lanes store z row0 ----
        #pragma unroll
        for (int tile = 0; tile < NT; ++tile) {
            f32x4 acc = {0.0f, 0.0f, 0.0f, 0.0f};
            acc = __builtin_amdgcn_mfma_f32_16x16x32_f16(a0, bf0[tile], acc, 0, 0, 0);
            acc = __builtin_amdgcn_mfma_f32_16x16x32_f16(a1, bf1[tile], acc, 0, 0, 0);
            if (q == 0) zsh[tile * 16 + ln16] = acc[0];   // row 0 = the batch
        }

        // ---- act (same-wave DS ordering guarantees z visible) ----
        const float zi = zsh[u]           + fmaf(xt, wx_i, b_i);
        const float zf = zsh[HID + u]     + fmaf(xt, wx_f, b_f);
        const float zg = zsh[2 * HID + u] + fmaf(xt, wx_g, b_g);
        const float zo = zsh[3 * HID + u] + fmaf(xt, wx_o, b_o);
        const float ig = fast_sigmoid(zi);
        const float fg = fast_sigmoid(zf);
        const float gg = fast_tanh(zg);
        const float og = fast_sigmoid(zo);
        c = fmaf(fg, c, ig * gg);
        h = og * fast_tanh(c);
        xt = xt_next;
    }

    // out[b] = h . Wd + bd
    float v = (lane < HID) ? h * wd_u : 0.0f;
    #pragma unroll
    for (int off = 32; off > 0; off >>= 1) v += __shfl_down(v, off);
    if (lane == 0) out[b] = v + bd[0];
}

extern "C" void kernel_launch(void* const* d_in, const int* in_sizes, int n_in,
                              void* d_out, int out_size, void* d_ws, size_t ws_size,
                              hipStream_t stream) {
    const float* x    = (const float*)d_in[0];  // [1024, 2048, 1]
    const float* Wx   = (const float*)d_in[1];  // [1, 200]
    const float* Wh   = (const float*)d_in[2];  // [50, 200]
    const float* bias = (const float*)d_in[3];  // [200]
    const float* Wd   = (const float*)d_in[4];  // [50, 1]
    const float* bd   = (const float*)d_in[5];  // [1]
    float* out = (float*)d_out;                 // [1024, 1]

    lstm_wmfma_kernel<<<dim3(NBATCH), dim3(64), 0, stream>>>(
        x, Wx, Wh, bias, Wd, bd, out);
}